// Round 6
// baseline (431.413 us; speedup 1.0000x reference)
//
#include <hip/hip_runtime.h>
#include <stdint.h>

typedef __bf16 bf16x8 __attribute__((ext_vector_type(8)));
typedef float floatx4 __attribute__((ext_vector_type(4)));

__device__ __forceinline__ void gload_lds16(const void* g, void* l) {
    __builtin_amdgcn_global_load_lds((const __attribute__((address_space(1))) void*)g,
                                     (__attribute__((address_space(3))) void*)l, 16, 0, 0);
}

__device__ __forceinline__ uint16_t f2bf(float f) {
    uint32_t u = __float_as_uint(f);
    u += 0x7fff + ((u >> 16) & 1);   // RNE
    return (uint16_t)(u >> 16);
}
__device__ __forceinline__ uint32_t f2bf2(float lo, float hi) {
    return (uint32_t)f2bf(lo) | ((uint32_t)f2bf(hi) << 16);
}

// ---- fused normalize_adj + sparse row gather ------------------------------
struct AmulSM {
    float vv[256];
    int   jj[256];
    float part[4];
    int   wcnt[4];
    int   woff[4];
    float sinv;
    int   n0;
};

__device__ __forceinline__ void amul_body(const float* __restrict__ adj,
                                          const float* __restrict__ H,
                                          uint16_t* __restrict__ outp,
                                          int b, int i, int tid, AmulSM* sm)
{
    const float* A = adj + ((size_t)b << 16);
    float aij = A[(i << 8) + tid];
    float aji = A[(tid << 8) + i];
    float v = fmaxf(aij, aji);
    if (tid == i) v += 1.0f;

    float s = v;
    #pragma unroll
    for (int off = 32; off > 0; off >>= 1) s += __shfl_down(s, off);

    bool pred = v != 0.0f;
    unsigned long long m = __ballot(pred);
    int wid = tid >> 6;
    if ((tid & 63) == 0) { sm->part[wid] = s; sm->wcnt[wid] = (int)__popcll(m); }
    __syncthreads();
    if (tid == 0) {
        float t = sm->part[0] + sm->part[1] + sm->part[2] + sm->part[3];
        sm->sinv = t > 0.0f ? 1.0f / t : 0.0f;
        int o = 0;
        #pragma unroll
        for (int w = 0; w < 4; ++w) { sm->woff[w] = o; o += sm->wcnt[w]; }
        sm->n0 = o;
    }
    __syncthreads();
    if (pred) {
        int pos = sm->woff[wid] + (int)__popcll(m & ((1ull << (tid & 63)) - 1ull));
        sm->vv[pos] = v * sm->sinv;
        sm->jj[pos] = tid;
    }
    __syncthreads();

    const int n0 = sm->n0;
    const int f0 = tid * 8;
    const float* Hb = H + (((size_t)b) << 8) * 2048;
    float acc[8] = {};
    for (int c = 0; c < n0; ++c) {
        float av = sm->vv[c];
        const float* hp = Hb + (size_t)sm->jj[c] * 2048 + f0;
        float4 p = *(const float4*)hp;
        float4 q = *(const float4*)(hp + 4);
        acc[0] += av * p.x; acc[1] += av * p.y; acc[2] += av * p.z; acc[3] += av * p.w;
        acc[4] += av * q.x; acc[5] += av * q.y; acc[6] += av * q.z; acc[7] += av * q.w;
    }
    uint4 o;
    o.x = f2bf2(acc[0], acc[1]);
    o.y = f2bf2(acc[2], acc[3]);
    o.z = f2bf2(acc[4], acc[5]);
    o.w = f2bf2(acc[6], acc[7]);
    *(uint4*)(outp + (((size_t)b << 8) + i) * 2048 + f0) = o;
}

// XCD-swizzled (b,i) for amul grids of 1024: XCD x owns one batch's H (2MB L2)
__device__ __forceinline__ void amul_swizzle(int bid, int& b, int& i) {
    int x = bid & 7, g = bid >> 3;      // assume XCD = bid % 8 (round-robin)
    b = x >> 1;
    i = ((x & 1) << 7) + g;             // g in [0,128)
}

// ---- dispatch 1: amul#1 | wT | W1-transpose | pad_x (inputs only) ---------
//   [0, 1024)        amul#1: gbf = a @ nodes (bf16)
//   [1024, 3072)     conv_w -> wT bf16
//   [3072, 4096)     W1 -> bf16 transpose
//   [4096, 28768)    pad_x
#define PR_AM 1024
#define PR_W  3072
#define PR_T  4096
#define PR_N  28768

__global__ __launch_bounds__(256)
void k_prep(const float* __restrict__ x, uint32_t* __restrict__ xpad,
            const float* __restrict__ w, uint16_t* __restrict__ wT,
            const float* __restrict__ W1, uint16_t* __restrict__ W1T,
            const float* __restrict__ adj, const float* __restrict__ nodes,
            uint16_t* __restrict__ gbf)
{
    __shared__ union {
        float  wbuf[6144];
        float  tile[64][65];
        AmulSM am;
    } sm;
    const int bid = blockIdx.x;
    const int tid = threadIdx.x;

    if (bid < PR_AM) {
        int b, i; amul_swizzle(bid, b, i);
        amul_body(adj, nodes, gbf, b, i, tid, &sm.am);
    } else if (bid < PR_W) {
        // conv_w [o][i][h] -> wT [o][h*2048+i] bf16 (LDS-staged)
        int o = bid - PR_AM;
        const float* src = w + (size_t)o * 6144;
        uint16_t*    dst = wT + (size_t)o * 6144;
        #pragma unroll
        for (int it = 0; it < 24; ++it)
            sm.wbuf[it * 256 + tid] = src[it * 256 + tid];
        __syncthreads();
        #pragma unroll
        for (int h = 0; h < 3; ++h)
            #pragma unroll
            for (int c = 0; c < 8; ++c) {
                int i = c * 256 + tid;
                dst[h * 2048 + i] = f2bf(sm.wbuf[i * 3 + h]);  // stride-3: conflict-free
            }
    } else if (bid < PR_T) {
        // W1 [2048][2048] -> bf16 transpose
        int t  = bid - PR_W;
        int by = (t >> 5) & 31;
        int bx = t & 31;
        int tx = tid & 63, ty = tid >> 6;
        for (int rr = ty; rr < 64; rr += 4)
            sm.tile[rr][tx] = W1[(size_t)(by * 64 + rr) * 2048 + bx * 64 + tx];
        __syncthreads();
        for (int rr = ty; rr < 64; rr += 4)
            W1T[(size_t)(bx * 64 + rr) * 2048 + by * 64 + tx] = f2bf(sm.tile[tx][rr]);
    } else {
        // x [12,512,2048] f32 -> xpad [12,514,2048] bf16 (zero pad rows)
        int idx2 = (bid - PR_T) * 256 + tid;
        int i2   = idx2 & 1023;
        int tmp  = idx2 >> 10;                      // b*514 + tt
        int b    = tmp / 514;
        int tt   = tmp - b * 514;
        float2 v = {0.0f, 0.0f};
        if (tt >= 1 && tt <= 512)
            v = *(const float2*)(x + ((size_t)(b * 512 + tt - 1) << 11) + i2 * 2);
        xpad[idx2] = f2bf2(v.x, v.y);
    }
}

// ---- dispatch 2: conv GEMM (768) || gemm64#1 (512) || W2-transpose (1024) -
__global__ __launch_bounds__(256)
void k_big(const uint16_t* __restrict__ xpad, const uint16_t* __restrict__ wmT,
           float* __restrict__ feats, const float* __restrict__ conv_b,
           const uint16_t* __restrict__ gbf, const uint16_t* __restrict__ W1T,
           float* __restrict__ h, const float* __restrict__ b1,
           const float* __restrict__ W2, uint16_t* __restrict__ W2T)
{
    __shared__ __align__(16) union {
        uint16_t u16[8192];     // conv: As[4096]+Bs[4096]; g64: As[2048]+Bs[2048]
        float    tile[64][65];  // W2 transpose
    } sm;
    const int bid  = blockIdx.x;
    const int tid  = threadIdx.x;
    const int lane = tid & 63;
    const int wave = tid >> 6;
    const int lm   = lane & 15;
    const int kq   = (lane >> 4) * 8;
    const int lq   = lane >> 4;
    const int srow  = tid >> 2;
    const int skcol = (tid & 3) * 8;

    if (bid < 768) {
        // ---------------- conv GEMM 128x128, K=6144, XCD-swizzled ----------
        // XCD x (=bid%8) owns rt-tiles [12*(x>>1),+12) x ct-tiles [8*(x&1),+8):
        // per-K-iter footprint 160 KB -> L2-resident, A 8-way / B 12-way reuse.
        uint16_t* As = sm.u16;
        uint16_t* Bs = sm.u16 + 4096;
        const int xc = bid & 7;
        const int g  = bid >> 3;            // 0..95
        const int rt = (12 * (xc >> 1) + (g % 12)) * 128;
        const int ct = (8 * (xc & 1) + (g / 12)) * 128;
        const int wm = (wave >> 1) * 64;
        const int wn = (wave & 1) * 64;

        floatx4 acc[4][4] = {};

        for (int k0 = 0; k0 < 6144; k0 += 32) {
            #pragma unroll
            for (int ii = 0; ii < 2; ++ii) {
                int row = ii * 64 + srow;
                int r  = rt + row;
                int b  = r >> 9;
                int t  = r & 511;
                int kk = k0 + skcol;
                int hh = kk >> 11;
                int ic = kk & 2047;
                gload_lds16(xpad + ((size_t)(b * 514 + t + hh) << 11) + ic,
                            &As[ii * 2048 + tid * 8]);
                gload_lds16(wmT + (size_t)(ct + row) * 6144 + k0 + skcol,
                            &Bs[ii * 2048 + tid * 8]);
            }
            __syncthreads();

            bf16x8 af[4], bfr[4];
            #pragma unroll
            for (int mt = 0; mt < 4; ++mt)
                af[mt] = *(const bf16x8*)&As[(wm + mt * 16 + lm) * 32 + kq];
            #pragma unroll
            for (int nt = 0; nt < 4; ++nt)
                bfr[nt] = *(const bf16x8*)&Bs[(wn + nt * 16 + lm) * 32 + kq];
            #pragma unroll
            for (int mt = 0; mt < 4; ++mt)
                #pragma unroll
                for (int nt = 0; nt < 4; ++nt)
                    acc[mt][nt] = __builtin_amdgcn_mfma_f32_16x16x32_bf16(af[mt], bfr[nt], acc[mt][nt], 0, 0, 0);
            __syncthreads();
        }

        #pragma unroll
        for (int mt = 0; mt < 4; ++mt)
            #pragma unroll
            for (int nt = 0; nt < 4; ++nt) {
                int col = ct + wn + nt * 16 + lm;
                float bv = conv_b[col];
                #pragma unroll
                for (int r = 0; r < 4; ++r) {
                    int row = rt + wm + mt * 16 + lq * 4 + r;
                    feats[(size_t)row * 2048 + col] = fmaxf(acc[mt][nt][r] + bv, 0.0f);
                }
            }
    } else if (bid < 1280) {
        // ---------------- gemm64#1: h = relu(gbf @ W1T^T + b1) -------------
        // XCD x owns 4 ct-tiles (B 1MB L2-resident), all 16 rt-tiles.
        uint16_t* As = sm.u16;
        uint16_t* Bs = sm.u16 + 2048;
        const int t  = bid - 768;
        const int xc = t & 7;
        const int g  = t >> 3;              // 0..63
        const int rt = (g & 15) * 64;
        const int ct = (4 * xc + (g >> 4)) * 64;
        const int wm = (wave >> 1) * 32;
        const int wn = (wave & 1) * 32;

        const size_t abase = (size_t)(rt + srow) * 2048 + skcol;
        const size_t bbase = (size_t)(ct + srow) * 2048 + skcol;

        floatx4 acc[2][2] = {};

        for (int k0 = 0; k0 < 2048; k0 += 32) {
            gload_lds16(gbf + abase + k0, &As[tid * 8]);
            gload_lds16(W1T + bbase + k0, &Bs[tid * 8]);
            __syncthreads();

            bf16x8 af[2], bfr[2];
            #pragma unroll
            for (int mt = 0; mt < 2; ++mt)
                af[mt] = *(const bf16x8*)&As[(wm + mt * 16 + lm) * 32 + kq];
            #pragma unroll
            for (int nt = 0; nt < 2; ++nt)
                bfr[nt] = *(const bf16x8*)&Bs[(wn + nt * 16 + lm) * 32 + kq];
            #pragma unroll
            for (int mt = 0; mt < 2; ++mt)
                #pragma unroll
                for (int nt = 0; nt < 2; ++nt)
                    acc[mt][nt] = __builtin_amdgcn_mfma_f32_16x16x32_bf16(af[mt], bfr[nt], acc[mt][nt], 0, 0, 0);
            __syncthreads();
        }

        #pragma unroll
        for (int mt = 0; mt < 2; ++mt)
            #pragma unroll
            for (int nt = 0; nt < 2; ++nt) {
                int col = ct + wn + nt * 16 + lm;
                float bv = b1[col];
                #pragma unroll
                for (int r = 0; r < 4; ++r) {
                    int row = rt + wm + mt * 16 + lq * 4 + r;
                    h[(size_t)row * 2048 + col] = fmaxf(acc[mt][nt][r] + bv, 0.0f);
                }
            }
    } else {
        // ---------------- W2 -> W2T bf16 transpose (tail filler) -----------
        int t  = bid - 1280;
        int by = (t >> 5) & 31;
        int bx = t & 31;
        int tx = tid & 63, ty = tid >> 6;
        for (int rr = ty; rr < 64; rr += 4)
            sm.tile[rr][tx] = W2[(size_t)(by * 64 + rr) * 2048 + bx * 64 + tx];
        __syncthreads();
        for (int rr = ty; rr < 64; rr += 4)
            W2T[(size_t)(bx * 64 + rr) * 2048 + by * 64 + tx] = f2bf(sm.tile[tx][rr]);
    }
}

// ---- dispatch 3: ahb = a @ h (bf16), normalize folded in, XCD-swizzled ----
__global__ __launch_bounds__(256)
void k_amul(const float* __restrict__ adj, const float* __restrict__ H,
            uint16_t* __restrict__ outp)
{
    __shared__ AmulSM sm;
    int b, i; amul_swizzle(blockIdx.x, b, i);
    amul_body(adj, H, outp, b, i, threadIdx.x, &sm);
}

// ---- dispatch 4: out = ahb @ W2T^T + b2, XCD-swizzled 64x64 ---------------
__global__ __launch_bounds__(256)
void k_gemm64(const uint16_t* __restrict__ A, const uint16_t* __restrict__ BT,
              float* __restrict__ C, const float* __restrict__ bias)
{
    __shared__ __align__(16) uint16_t As[64 * 32];
    __shared__ __align__(16) uint16_t Bs[64 * 32];
    const int tid  = threadIdx.x;
    const int bid  = blockIdx.x;
    const int xc   = bid & 7;
    const int g    = bid >> 3;              // 0..63
    const int rt   = (g & 15) * 64;
    const int ct   = (4 * xc + (g >> 4)) * 64;
    const int lane = tid & 63;
    const int wave = tid >> 6;
    const int wm   = (wave >> 1) * 32;
    const int wn   = (wave & 1) * 32;
    const int lm   = lane & 15;
    const int kq   = (lane >> 4) * 8;
    const int srow  = tid >> 2;
    const int skcol = (tid & 3) * 8;

    const size_t abase = (size_t)(rt + srow) * 2048 + skcol;
    const size_t bbase = (size_t)(ct + srow) * 2048 + skcol;

    floatx4 acc[2][2] = {};

    for (int k0 = 0; k0 < 2048; k0 += 32) {
        gload_lds16(A  + abase + k0, &As[tid * 8]);
        gload_lds16(BT + bbase + k0, &Bs[tid * 8]);
        __syncthreads();

        bf16x8 af[2], bfr[2];
        #pragma unroll
        for (int mt = 0; mt < 2; ++mt)
            af[mt] = *(const bf16x8*)&As[(wm + mt * 16 + lm) * 32 + kq];
        #pragma unroll
        for (int nt = 0; nt < 2; ++nt)
            bfr[nt] = *(const bf16x8*)&Bs[(wn + nt * 16 + lm) * 32 + kq];
        #pragma unroll
        for (int mt = 0; mt < 2; ++mt)
            #pragma unroll
            for (int nt = 0; nt < 2; ++nt)
                acc[mt][nt] = __builtin_amdgcn_mfma_f32_16x16x32_bf16(af[mt], bfr[nt], acc[mt][nt], 0, 0, 0);
        __syncthreads();
    }

    const int lq = lane >> 4;
    #pragma unroll
    for (int mt = 0; mt < 2; ++mt)
        #pragma unroll
        for (int nt = 0; nt < 2; ++nt) {
            int col = ct + wn + nt * 16 + lm;
            float bv = bias[col];
            #pragma unroll
            for (int r = 0; r < 4; ++r) {
                int row = rt + wm + mt * 16 + lq * 4 + r;
                C[(size_t)row * 2048 + col] = acc[mt][nt][r] + bv;
            }
        }
}

// ---- launch ---------------------------------------------------------------

extern "C" void kernel_launch(void* const* d_in, const int* in_sizes, int n_in,
                              void* d_out, int out_size, void* d_ws, size_t ws_size,
                              hipStream_t stream)
{
    const float* x      = (const float*)d_in[0];
    const float* nodes  = (const float*)d_in[1];
    const float* adj    = (const float*)d_in[2];
    const float* conv_w = (const float*)d_in[3];
    const float* conv_b = (const float*)d_in[4];
    const float* W1     = (const float*)d_in[5];
    const float* b1     = (const float*)d_in[6];
    const float* W2     = (const float*)d_in[7];
    const float* b2     = (const float*)d_in[8];
    float* out = (float*)d_out;

    char* ws = (char*)d_ws;
    uint16_t* xpad   = (uint16_t*)(ws);                 // 25,288,704
    uint16_t* wmT    = (uint16_t*)(ws + 25288704);      // 25,165,824
    uint16_t* W1T    = (uint16_t*)(ws + 50454528);      // 8,388,608
    uint16_t* W2T    = (uint16_t*)(ws + 58843136);      // 8,388,608
    uint16_t* gbf    = (uint16_t*)(ws + 67231744);      // 4,194,304  a@nodes (bf16)
    float*    h      = (float*)   (ws + 71426048);      // 8,388,608  relu(gbf@W1+b1)
    uint16_t* ahb    = (uint16_t*)(ws + 79814656);      // 4,194,304  a@h (bf16)

    // d1: everything that depends only on inputs
    k_prep<<<PR_N, 256, 0, stream>>>(x, (uint32_t*)xpad, conv_w, wmT,
                                     W1, W1T, adj, nodes, gbf);
    // d2: conv GEMM || gemm64#1 || W2-transpose co-scheduled
    k_big<<<2304, 256, 0, stream>>>(xpad, wmT, out, conv_b, gbf, W1T, h, b1, W2, W2T);
    // d3: ahb = a @ h
    k_amul<<<1024, 256, 0, stream>>>(adj, h, ahb);
    // d4: out_gcn = ahb @ W2 + b2
    k_gemm64<<<512, 256, 0, stream>>>(ahb, W2T, out + 12582912, b2);
}